// Round 1
// baseline (324.831 us; speedup 1.0000x reference)
//
#include <hip/hip_runtime.h>
#include <math.h>

// ListwiseSmoothINDCGKLoss: bs x ll (16384 x 2048) fp32 scores + graded labels
// -> scalar sum(1 - ndcg@10). One 256-thread block per row; row data held in
// registers across the K=10 sequential softmax passes.

constexpr int LL      = 2048;
constexpr int THREADS = 256;          // 4 waves
constexpr int EPT     = LL / THREADS; // 8 elements per thread
constexpr int KTOP    = 10;
constexpr float ALPHA = 10.0f;
constexpr float DELTA = 0.1f;
constexpr float EPSF  = 1e-10f;
constexpr float LOG2E = 1.44269504088896340736f;

// log2(k+2) for k=0..9
__device__ const float DENOM[KTOP] = {
    1.0f,              1.58496250072116f, 2.0f,              2.32192809488736f,
    2.58496250072116f, 2.80735492205760f, 3.0f,              3.16992500144231f,
    3.32192809488736f, 3.45943161863730f};

__device__ __forceinline__ float wave_max(float v) {
#pragma unroll
    for (int o = 32; o; o >>= 1) v = fmaxf(v, __shfl_xor(v, o, 64));
    return v;
}
__device__ __forceinline__ float wave_min(float v) {
#pragma unroll
    for (int o = 32; o; o >>= 1) v = fminf(v, __shfl_xor(v, o, 64));
    return v;
}
__device__ __forceinline__ float wave_sum(float v) {
#pragma unroll
    for (int o = 32; o; o >>= 1) v += __shfl_xor(v, o, 64);
    return v;
}

// Block reductions across 4 waves via 8-float LDS buffer.
// Pattern: sync (guard previous read), write, sync, read.
__device__ __forceinline__ float block_max(float v, float* sm) {
    v = wave_max(v);
    __syncthreads();
    if ((threadIdx.x & 63) == 0) sm[threadIdx.x >> 6] = v;
    __syncthreads();
    return fmaxf(fmaxf(sm[0], sm[1]), fmaxf(sm[2], sm[3]));
}
__device__ __forceinline__ float block_min(float v, float* sm) {
    v = wave_min(v);
    __syncthreads();
    if ((threadIdx.x & 63) == 0) sm[threadIdx.x >> 6] = v;
    __syncthreads();
    return fminf(fminf(sm[0], sm[1]), fminf(sm[2], sm[3]));
}
__device__ __forceinline__ void block_sum2(float& a, float& b, float* sm) {
    a = wave_sum(a);
    b = wave_sum(b);
    __syncthreads();
    if ((threadIdx.x & 63) == 0) {
        sm[threadIdx.x >> 6]     = a;
        sm[4 + (threadIdx.x >> 6)] = b;
    }
    __syncthreads();
    a = (sm[0] + sm[1]) + (sm[2] + sm[3]);
    b = (sm[4] + sm[5]) + (sm[6] + sm[7]);
}

__global__ __launch_bounds__(THREADS) void ndcg_loss_kernel(
    const float* __restrict__ s, const float* __restrict__ label,
    float* __restrict__ out) {
    __shared__ float sm[8];
    __shared__ int   hist[5];

    const int    tid  = threadIdx.x;
    const size_t row  = blockIdx.x;
    const float* srow = s + row * (size_t)LL;
    const float* lrow = label + row * (size_t)LL;

    // --- vectorized row load: thread t owns elems [t*8, t*8+8) ---
    float4 a0 = ((const float4*)srow)[tid * 2];
    float4 a1 = ((const float4*)srow)[tid * 2 + 1];
    float4 b0 = ((const float4*)lrow)[tid * 2];
    float4 b1 = ((const float4*)lrow)[tid * 2 + 1];
    float  sv[EPT] = {a0.x, a0.y, a0.z, a0.w, a1.x, a1.y, a1.z, a1.w};
    float  lv[EPT] = {b0.x, b0.y, b0.z, b0.w, b1.x, b1.y, b1.z, b1.w};

    // --- row min of s ---
    float mn = sv[0];
#pragma unroll
    for (int j = 1; j < EPT; ++j) mn = fminf(mn, sv[j]);
    mn = block_min(mn, sm);

    // fold ALPHA*log2(e) into the shifted scores: b = s2*prod ; softmax in base-2
    float s2[EPT];
#pragma unroll
    for (int j = 0; j < EPT; ++j) s2[j] = (sv[j] - mn) * (ALPHA * LOG2E);

    // --- label histogram (values are exact integers 0..4) for IDCG top-10 ---
    if (tid < 5) hist[tid] = 0;
    __syncthreads();
    int c[5] = {0, 0, 0, 0, 0};
#pragma unroll
    for (int j = 0; j < EPT; ++j) c[(int)lv[j]]++;
#pragma unroll
    for (int v = 0; v < 5; ++v)
        if (c[v]) atomicAdd(&hist[v], c[v]);
    __syncthreads();

    float idcg = EPSF;
    {
        int slot = 0;
        for (int v = 4; v >= 0 && slot < KTOP; --v) {
            int   cnt = hist[v];
            float e2  = exp2f((float)v);
            while (cnt > 0 && slot < KTOP) {
                idcg += e2 / DENOM[slot];
                ++slot;
                --cnt;
            }
        }
    }
    __syncthreads();  // hist/sm free for reuse

    // --- K sequential softmax passes, all in registers ---
    float prod[EPT];
#pragma unroll
    for (int j = 0; j < EPT; ++j) prod[j] = 1.0f;
    float dcg = EPSF;

#pragma unroll
    for (int k = 0; k < KTOP; ++k) {
        float e[EPT];
        float m = -INFINITY;
#pragma unroll
        for (int j = 0; j < EPT; ++j) {
            e[j] = s2[j] * prod[j];  // = B * log2(e)
            m    = fmaxf(m, e[j]);
        }
        m = block_max(m, sm);

        float se = 0.0f, sle = 0.0f;
#pragma unroll
        for (int j = 0; j < EPT; ++j) {
            float ex = exp2f(e[j] - m);
            e[j]     = ex;
            se += ex;
            sle += lv[j] * ex;
        }
        block_sum2(se, sle, sm);

        float inv = 1.0f / se;
        float rel = sle * inv;           // sum(label * softmax)
        dcg += exp2f(rel) / DENOM[k];

        const float c09 = 1.0f - DELTA;  // 0.9
#pragma unroll
        for (int j = 0; j < EPT; ++j) prod[j] = prod[j] * (c09 - e[j] * inv);
    }

    if (tid == 0) {
        float loss = 1.0f - dcg / idcg;
        atomicAdd(out, loss);
    }
}

__global__ void zero_out_kernel(float* out) { out[0] = 0.0f; }

extern "C" void kernel_launch(void* const* d_in, const int* in_sizes, int n_in,
                              void* d_out, int out_size, void* d_ws,
                              size_t ws_size, hipStream_t stream) {
    const float* s     = (const float*)d_in[0];
    const float* label = (const float*)d_in[1];
    float*       out   = (float*)d_out;

    const int bs = in_sizes[0] / LL;

    zero_out_kernel<<<1, 1, 0, stream>>>(out);
    ndcg_loss_kernel<<<bs, THREADS, 0, stream>>>(s, label, out);
}

// Round 2
// 194.771 us; speedup vs baseline: 1.6678x; 1.6678x over previous
//
#include <hip/hip_runtime.h>
#include <math.h>

// ListwiseSmoothINDCGKLoss: bs x ll (16384 x 2048) fp32 scores + graded labels
// -> scalar sum(1 - ndcg@10).
// One 256-thread block per row, 8 elems/thread held in registers.
// Key ideas:
//  - softmax scale-invariance: rel = sle/se and approx = ex/se don't need the
//    exact row max; any M in [truemax, truemax+~118] is numerically safe.
//    truemax >= 0 (row-min of s2 is exactly 0), |prod_k| <= 0.9^k, so
//    M_k = min(s2max * 0.9^k, 118) works -> NO per-k max reduction.
//  - one barrier per k (ping-pong LDS), ds_swizzle xor-reduce (1 instr/step).
//  - no divides: rcp + reciprocal-denominator constants.
//  - IDCG via packed label histogram + closed form (labels are ints 0..4).

constexpr int LL      = 2048;
constexpr int THREADS = 256;          // 4 waves
constexpr int EPT     = LL / THREADS; // 8
constexpr int KTOP    = 10;
constexpr float ALPHA  = 10.0f;
constexpr float EPSF   = 1e-10f;
constexpr float LOG2E  = 1.44269504088896340736f;
constexpr float MCLAMP = 118.0f;

// 1 / log2(k+2), k = 0..9
__device__ constexpr float INVDEN[KTOP] = {
    1.0f,                0.6309297535714574f, 0.5f,                0.43067655807339306f,
    0.38685280723454163f,0.356207187108022f,  0.3333333333333333f, 0.31546487678572877f,
    0.30102999566398114f,0.2890648263178878f};

template <int PAT>
__device__ __forceinline__ float swzf(float v) {
    return __int_as_float(__builtin_amdgcn_ds_swizzle(__float_as_int(v), PAT));
}
template <int PAT>
__device__ __forceinline__ int swzi(int v) {
    return __builtin_amdgcn_ds_swizzle(v, PAT);
}

// reduce within each 32-lane half (xor 1,2,4,8,16)
__device__ __forceinline__ void half_sum2(float& a, float& b) {
    a += swzf<0x041F>(a); b += swzf<0x041F>(b);
    a += swzf<0x081F>(a); b += swzf<0x081F>(b);
    a += swzf<0x101F>(a); b += swzf<0x101F>(b);
    a += swzf<0x201F>(a); b += swzf<0x201F>(b);
    a += swzf<0x401F>(a); b += swzf<0x401F>(b);
}
__device__ __forceinline__ void half_minmax(float& mn, float& mx) {
    mn = fminf(mn, swzf<0x041F>(mn)); mx = fmaxf(mx, swzf<0x041F>(mx));
    mn = fminf(mn, swzf<0x081F>(mn)); mx = fmaxf(mx, swzf<0x081F>(mx));
    mn = fminf(mn, swzf<0x101F>(mn)); mx = fmaxf(mx, swzf<0x101F>(mx));
    mn = fminf(mn, swzf<0x201F>(mn)); mx = fmaxf(mx, swzf<0x201F>(mx));
    mn = fminf(mn, swzf<0x401F>(mn)); mx = fmaxf(mx, swzf<0x401F>(mx));
}
__device__ __forceinline__ void half_isum3(int& a, int& b, int& c) {
    a += swzi<0x041F>(a); b += swzi<0x041F>(b); c += swzi<0x041F>(c);
    a += swzi<0x081F>(a); b += swzi<0x081F>(b); c += swzi<0x081F>(c);
    a += swzi<0x101F>(a); b += swzi<0x101F>(b); c += swzi<0x101F>(c);
    a += swzi<0x201F>(a); b += swzi<0x201F>(b); c += swzi<0x201F>(c);
    a += swzi<0x401F>(a); b += swzi<0x401F>(b); c += swzi<0x401F>(c);
}

__global__ __launch_bounds__(THREADS, 4) void ndcg_loss_kernel(
    const float* __restrict__ s, const float* __restrict__ label,
    float* __restrict__ ws, float* __restrict__ out, int mode) {
    __shared__ __align__(16) float red[2][16];  // ping-pong: 8 half-waves x float2
    __shared__ int ibuf[24];                    // 8 half-waves x 3 packed counts

    const int    tid  = threadIdx.x;
    const size_t row  = blockIdx.x;
    const int    half = tid >> 5;  // 0..7

    const float4* s4 = (const float4*)(s + row * (size_t)LL);
    const float4* l4 = (const float4*)(label + row * (size_t)LL);
    float4 a0 = s4[tid * 2], a1 = s4[tid * 2 + 1];
    float4 b0 = l4[tid * 2], b1 = l4[tid * 2 + 1];
    float  sv[EPT] = {a0.x, a0.y, a0.z, a0.w, a1.x, a1.y, a1.z, a1.w};
    float  lv[EPT] = {b0.x, b0.y, b0.z, b0.w, b1.x, b1.y, b1.z, b1.w};

    // ---- row min & max of s (one block reduction, once) ----
    float mn = sv[0], mx = sv[0];
#pragma unroll
    for (int j = 1; j < EPT; ++j) { mn = fminf(mn, sv[j]); mx = fmaxf(mx, sv[j]); }
    half_minmax(mn, mx);
    if ((tid & 31) == 0) ((float2*)red[0])[half] = make_float2(mn, mx);
    __syncthreads();
    {
        const float4* r = (const float4*)red[0];
        float4 q0 = r[0], q1 = r[1], q2 = r[2], q3 = r[3];
        mn = fminf(fminf(fminf(q0.x, q1.x), fminf(q2.x, q3.x)),
                   fminf(fminf(q0.z, q1.z), fminf(q2.z, q3.z)));
        mx = fmaxf(fmaxf(fmaxf(q0.y, q1.y), fmaxf(q2.y, q3.y)),
                   fmaxf(fmaxf(q0.w, q1.w), fmaxf(q2.w, q3.w)));
    }

    float s2[EPT];
#pragma unroll
    for (int j = 0; j < EPT; ++j) s2[j] = (sv[j] - mn) * (ALPHA * LOG2E);
    float M = fminf((mx - mn) * (ALPHA * LOG2E), MCLAMP);

    // ---- label histogram (exact ints 0..4) -> packed counts -> IDCG ----
    int c0 = 0, c1 = 0, c2 = 0, c3 = 0, c4 = 0;
#pragma unroll
    for (int j = 0; j < EPT; ++j) {
        c0 += (lv[j] == 0.0f); c1 += (lv[j] == 1.0f); c2 += (lv[j] == 2.0f);
        c3 += (lv[j] == 3.0f); c4 += (lv[j] == 4.0f);
    }
    int A = c0 | (c1 << 16), B = c2 | (c3 << 16), C = c4;
    half_isum3(A, B, C);
    if ((tid & 31) == 0) { ibuf[half * 3] = A; ibuf[half * 3 + 1] = B; ibuf[half * 3 + 2] = C; }
    __syncthreads();  // also orders red[0] reads above vs k=0 writes below
    A = 0; B = 0; C = 0;
#pragma unroll
    for (int h = 0; h < 8; ++h) { A += ibuf[h * 3]; B += ibuf[h * 3 + 1]; C += ibuf[h * 3 + 2]; }
    const int n4 = C, n3 = n4 + (B >> 16), n2 = n3 + (B & 0xFFFF), n1 = n2 + (A >> 16);
    float idcg = EPSF;
#pragma unroll
    for (int slot = 0; slot < KTOP; ++slot) {
        int v = (slot < n4) + (slot < n3) + (slot < n2) + (slot < n1);
        idcg = fmaf((float)(1 << v), INVDEN[slot], idcg);
    }

    // ---- K sequential scale-invariant softmax passes ----
    float prod[EPT];
#pragma unroll
    for (int j = 0; j < EPT; ++j) prod[j] = 1.0f;
    float dcg = EPSF;

#pragma unroll
    for (int k = 0; k < KTOP; ++k) {
        float ex[EPT];
        float se = 0.0f, sle = 0.0f;
#pragma unroll
        for (int j = 0; j < EPT; ++j) {
            float x = __builtin_amdgcn_exp2f(fmaf(s2[j], prod[j], -M));
            ex[j] = x;
            se += x;
            sle = fmaf(lv[j], x, sle);
        }
        half_sum2(se, sle);
        if ((tid & 31) == 0) ((float2*)red[k & 1])[half] = make_float2(se, sle);
        __syncthreads();
        const float4* r = (const float4*)red[k & 1];
        float4 q0 = r[0], q1 = r[1], q2 = r[2], q3 = r[3];
        se  = ((q0.x + q1.x) + (q2.x + q3.x)) + ((q0.z + q1.z) + (q2.z + q3.z));
        sle = ((q0.y + q1.y) + (q2.y + q3.y)) + ((q0.w + q1.w) + (q2.w + q3.w));

        float inv = __builtin_amdgcn_rcpf(se);
        dcg = fmaf(__builtin_amdgcn_exp2f(sle * inv), INVDEN[k], dcg);
#pragma unroll
        for (int j = 0; j < EPT; ++j) prod[j] *= fmaf(ex[j], -inv, 0.9f);
        M *= 0.9f;
    }

    if (tid == 0) {
        float loss = 1.0f - dcg / idcg;
        if (mode) atomicAdd(out, loss);
        else      ws[row] = loss;
    }
}

__global__ __launch_bounds__(256) void reduce_sum_kernel(
    const float* __restrict__ w, float* __restrict__ out, int n4) {
    __shared__ float sb[8];
    float acc = 0.0f;
    const float4* w4 = (const float4*)w;
    for (int i = threadIdx.x; i < n4; i += 256) {
        float4 q = w4[i];
        acc += (q.x + q.y) + (q.z + q.w);
    }
    float a = acc;
    a += swzf<0x041F>(a); a += swzf<0x081F>(a); a += swzf<0x101F>(a);
    a += swzf<0x201F>(a); a += swzf<0x401F>(a);
    if ((threadIdx.x & 31) == 0) sb[threadIdx.x >> 5] = a;
    __syncthreads();
    if (threadIdx.x == 0) {
        float t = 0.0f;
#pragma unroll
        for (int i = 0; i < 8; ++i) t += sb[i];
        out[0] = t;
    }
}

__global__ void zero_out_kernel(float* out) { out[0] = 0.0f; }

extern "C" void kernel_launch(void* const* d_in, const int* in_sizes, int n_in,
                              void* d_out, int out_size, void* d_ws,
                              size_t ws_size, hipStream_t stream) {
    const float* s     = (const float*)d_in[0];
    const float* label = (const float*)d_in[1];
    float*       out   = (float*)d_out;
    const int    bs    = in_sizes[0] / LL;

    if (ws_size >= (size_t)bs * sizeof(float)) {
        float* w = (float*)d_ws;
        ndcg_loss_kernel<<<bs, THREADS, 0, stream>>>(s, label, w, nullptr, 0);
        reduce_sum_kernel<<<1, 256, 0, stream>>>(w, out, bs / 4);
    } else {
        zero_out_kernel<<<1, 1, 0, stream>>>(out);
        ndcg_loss_kernel<<<bs, THREADS, 0, stream>>>(s, label, nullptr, out, 1);
    }
}